// Round 11
// baseline (1424.275 us; speedup 1.0000x reference)
//
#include <hip/hip_runtime.h>

#define N_NODES 150000
#define N_EDGES 2400000
#define D 32
#define NBUCK 1172                 // ceil(N/128)
#define CHUNK 4096
#define NCHK 586                   // ceil(E/CHUNK)

// ---------- pass A: per-chunk LDS histogram of buckets ----------
__global__ __launch_bounds__(256) void kA_hist(const int* __restrict__ dst,
                                               int* __restrict__ cnt) {
    __shared__ int bins[NBUCK];
    int t = threadIdx.x;
    for (int k = t; k < NBUCK; k += 256) bins[k] = 0;
    __syncthreads();
    int e0 = blockIdx.x * CHUNK;
#pragma unroll
    for (int r = 0; r < CHUNK / 256; ++r) {
        int e = e0 + r * 256 + t;
        if (e < N_EDGES) atomicAdd(&bins[dst[e] >> 7], 1);
    }
    __syncthreads();
    for (int k = t; k < NBUCK; k += 256) cnt[blockIdx.x * NBUCK + k] = bins[k];
}

// ---------- S1: per-bucket exclusive scan over chunks ----------
__global__ __launch_bounds__(256) void kS1(int* __restrict__ cnt, int* __restrict__ bstart) {
    __shared__ int tile[8][33];
    __shared__ int carry[32];
    int t = threadIdx.x;
    int tl = t & 31, tr = t >> 5;
    int b = blockIdx.x * 32 + tl;
    if (t < 32) carry[t] = 0;
    __syncthreads();
    for (int c0 = 0; c0 < NCHK; c0 += 8) {
        int c = c0 + tr;
        int v = (c < NCHK && b < NBUCK) ? cnt[c * NBUCK + b] : 0;
        tile[tr][tl] = v;
        __syncthreads();
        if (t < 32) {
            int s = carry[t];
#pragma unroll
            for (int r = 0; r < 8; ++r) { int x = tile[r][t]; tile[r][t] = s; s += x; }
            carry[t] = s;
        }
        __syncthreads();
        if (c < NCHK && b < NBUCK) cnt[c * NBUCK + b] = tile[tr][tl];
        __syncthreads();
    }
    if (t < 32 && b < NBUCK) bstart[b] = carry[t];
}

// ---------- single-block exclusive scan in place; a[m] = total ----------
__global__ void k_scan_small(int* __restrict__ a, int m) {
    __shared__ int s[256];
    __shared__ int carry;
    int t = threadIdx.x;
    if (t == 0) carry = 0;
    __syncthreads();
    for (int base = 0; base < m; base += 256) {
        int v = (base + t < m) ? a[base + t] : 0;
        s[t] = v;
        __syncthreads();
        for (int off = 1; off < 256; off <<= 1) {
            int add = (t >= off) ? s[t - off] : 0;
            __syncthreads();
            s[t] += add;
            __syncthreads();
        }
        int c0 = carry;
        if (base + t < m) a[base + t] = c0 + s[t] - v;
        int bsum = s[255];
        __syncthreads();
        if (t == 0) carry = c0 + bsum;
        __syncthreads();
    }
    if (t == 0) a[m] = carry;
}

// ---------- pass B: scatter packed edges into bucket-grouped ebuf ----------
// edges within a bucket stay in ORIGINAL (random-dst) order -> LDS-atomic friendly
__global__ __launch_bounds__(256) void kB_scatter(const int* __restrict__ src,
                                                  const int* __restrict__ dst,
                                                  const int* __restrict__ cnt,
                                                  const int* __restrict__ bstart,
                                                  int* __restrict__ ebuf) {
    __shared__ int lofs[NBUCK];
    int t = threadIdx.x;
    for (int k = t; k < NBUCK; k += 256)
        lofs[k] = bstart[k] + cnt[blockIdx.x * NBUCK + k];
    __syncthreads();
    int e0 = blockIdx.x * CHUNK;
#pragma unroll
    for (int r = 0; r < CHUNK / 256; ++r) {
        int e = e0 + r * 256 + t;
        if (e < N_EDGES) {
            int d = dst[e];
            int p = atomicAdd(&lofs[d >> 7], 1);
            ebuf[p] = src[e] | ((d & 127) << 18);  // src < 2^18
        }
    }
}

// ---------- D: per-bucket degree histogram -> dis, xd ----------
__global__ __launch_bounds__(256) void kD(const int* __restrict__ ebuf,
                                          const int* __restrict__ bstart,
                                          const float2* __restrict__ x,
                                          float* __restrict__ dis,
                                          float4* __restrict__ xd) {
    __shared__ int hist[128];
    int b = blockIdx.x, t = threadIdx.x;
    if (t < 128) hist[t] = 0;
    __syncthreads();
    int s0 = bstart[b], s1 = bstart[b + 1];
    for (int e = s0 + t; e < s1; e += 256) atomicAdd(&hist[ebuf[e] >> 18], 1);
    __syncthreads();
    int i = b * 128 + t;
    if (t < 128 && i < N_NODES) {
        float dz = rsqrtf((float)hist[t] + 1.0f);  // +1 self-loop
        dis[i] = dz;
        float2 xv = x[i];
        xd[i] = make_float4(xv.x, xv.y, dz, 0.f);
    }
}

// ---------- layer1 (+fc1 fused): bucket-resident LDS-atomic edge stream ----------
#define L1_EDGE(v, r)                                                             \
    {                                                                             \
        float h0 = fmaf((r).x, u0, fmaf((r).y, z0, q0)); h0 = h0 > 0.f ? h0 : 0.f;\
        float h1 = fmaf((r).x, u1, fmaf((r).y, z1, q1)); h1 = h1 > 0.f ? h1 : 0.f;\
        float h2 = fmaf((r).x, u2, fmaf((r).y, z2, q2)); h2 = h2 > 0.f ? h2 : 0.f;\
        float h3 = fmaf((r).x, u3, fmaf((r).y, z3, q3)); h3 = h3 > 0.f ? h3 : 0.f;\
        int ab = ((v) >> 18) * 33 + c * 4;                                        \
        atomicAdd(&acc[ab + 0], h0 * (r).z);                                      \
        atomicAdd(&acc[ab + 1], h1 * (r).z);                                      \
        atomicAdd(&acc[ab + 2], h2 * (r).z);                                      \
        atomicAdd(&acc[ab + 3], h3 * (r).z);                                      \
    }

__global__ __launch_bounds__(256) void k_l1(const int* __restrict__ ebuf,
                                            const int* __restrict__ bstart,
                                            const float4* __restrict__ xd,
                                            const float* __restrict__ W,   // fc1_w [2][32]
                                            const float* __restrict__ bf,  // fc1_b
                                            const float* __restrict__ Wc,  // conv1_w
                                            const float* __restrict__ bc,  // conv1_b
                                            float* __restrict__ hout) {
    __shared__ float acc[128 * 33];
    int b = blockIdx.x, t = threadIdx.x, f = t & 31, g = t >> 5;
    int n0 = b * 128;
    // init acc with self term: hs(own)*dz(own)
    {
        float w0 = W[f], w1 = W[D + f], bb = bf[f];
        for (int n = g; n < 128; n += 8) {
            int i = n0 + n;
            float v = 0.f;
            if (i < N_NODES) {
                float4 s = xd[i];  // broadcast within 32 lanes
                float h = fmaf(s.x, w0, fmaf(s.y, w1, bb));
                h = h > 0.f ? h : 0.f;
                v = h * s.z;
            }
            acc[n * 33 + f] = v;
        }
    }
    __syncthreads();
    int s0 = bstart[b], s1 = bstart[b + 1];
    int eg = t >> 3, c = t & 7;
    float u0 = W[c * 4 + 0], u1 = W[c * 4 + 1], u2 = W[c * 4 + 2], u3 = W[c * 4 + 3];
    float z0 = W[D + c * 4 + 0], z1 = W[D + c * 4 + 1], z2 = W[D + c * 4 + 2], z3 = W[D + c * 4 + 3];
    float q0 = bf[c * 4 + 0], q1 = bf[c * 4 + 1], q2 = bf[c * 4 + 2], q3 = bf[c * 4 + 3];
    int e = s0 + eg;
    for (; e + 96 < s1; e += 128) {
        int v0 = ebuf[e], v1 = ebuf[e + 32], v2 = ebuf[e + 64], v3 = ebuf[e + 96];
        float4 r0 = xd[v0 & 0x3FFFF];
        float4 r1 = xd[v1 & 0x3FFFF];
        float4 r2 = xd[v2 & 0x3FFFF];
        float4 r3 = xd[v3 & 0x3FFFF];
        L1_EDGE(v0, r0) L1_EDGE(v1, r1) L1_EDGE(v2, r2) L1_EDGE(v3, r3)
    }
    for (; e < s1; e += 32) {
        int v = ebuf[e];
        float4 r = xd[v & 0x3FFFF];
        L1_EDGE(v, r)
    }
    __syncthreads();
    // transform: out = relu((agg*di) @ Wc + bc) * di
    float wcol[D];
#pragma unroll
    for (int k = 0; k < D; ++k) wcol[k] = Wc[k * D + f];
    float bcf = bc[f];
    for (int n = g; n < 128; n += 8) {
        int i = n0 + n;
        if (i >= N_NODES) break;
        float di = xd[i].z;
        float a = 0.f;
#pragma unroll
        for (int k = 0; k < D; ++k) a = fmaf(acc[n * 33 + k], wcol[k], a);
        a *= di;
        float v = a + bcf;
        v = v > 0.f ? v : 0.f;
        hout[i * D + f] = v * di;
    }
}

// ---------- mid layer: bucket-resident LDS-atomic edge stream ----------
#define EDGE_ADD(v, r)                                                            \
    {                                                                             \
        int ab = ((v) >> 18) * 33 + c * 4;                                        \
        atomicAdd(&acc[ab + 0], (r).x);                                           \
        atomicAdd(&acc[ab + 1], (r).y);                                           \
        atomicAdd(&acc[ab + 2], (r).z);                                           \
        atomicAdd(&acc[ab + 3], (r).w);                                           \
    }

__global__ __launch_bounds__(256) void k_lmid(const int* __restrict__ ebuf,
                                              const int* __restrict__ bstart,
                                              const float* __restrict__ hsc,
                                              const float* __restrict__ dis,
                                              const float* __restrict__ W,
                                              const float* __restrict__ bias,
                                              float* __restrict__ hout) {
    __shared__ float acc[128 * 33];
    int b = blockIdx.x, t = threadIdx.x, f = t & 31, g = t >> 5;
    int n0 = b * 128;
    for (int n = g; n < 128; n += 8) {
        int i = n0 + n;
        acc[n * 33 + f] = (i < N_NODES) ? hsc[i * D + f] : 0.f;  // self term
    }
    __syncthreads();
    int s0 = bstart[b], s1 = bstart[b + 1];
    int eg = t >> 3, c = t & 7;
    const float4* rowf4 = (const float4*)hsc;
    int e = s0 + eg;
    for (; e + 96 < s1; e += 128) {
        int v0 = ebuf[e], v1 = ebuf[e + 32], v2 = ebuf[e + 64], v3 = ebuf[e + 96];
        float4 r0 = rowf4[(v0 & 0x3FFFF) * 8 + c];
        float4 r1 = rowf4[(v1 & 0x3FFFF) * 8 + c];
        float4 r2 = rowf4[(v2 & 0x3FFFF) * 8 + c];
        float4 r3 = rowf4[(v3 & 0x3FFFF) * 8 + c];
        EDGE_ADD(v0, r0) EDGE_ADD(v1, r1) EDGE_ADD(v2, r2) EDGE_ADD(v3, r3)
    }
    for (; e < s1; e += 32) {
        int v = ebuf[e];
        float4 r = rowf4[(v & 0x3FFFF) * 8 + c];
        EDGE_ADD(v, r)
    }
    __syncthreads();
    float wcol[D];
#pragma unroll
    for (int k = 0; k < D; ++k) wcol[k] = W[k * D + f];
    float bf = bias[f];
    for (int n = g; n < 128; n += 8) {
        int i = n0 + n;
        if (i >= N_NODES) break;
        float di = dis[i];
        float a = 0.f;
#pragma unroll
        for (int k = 0; k < D; ++k) a = fmaf(acc[n * 33 + k], wcol[k], a);
        a *= di;
        float v = a + bf;
        v = v > 0.f ? v : 0.f;
        hout[i * D + f] = v * di;
    }
}

// ---------- heads: same edge stream, dual transform + 32->1 dots ----------
__global__ __launch_bounds__(256) void k_lheads(
    const int* __restrict__ ebuf, const int* __restrict__ bstart,
    const float* __restrict__ hsc, const float* __restrict__ dis,
    const float* __restrict__ W1, const float* __restrict__ b1,
    const float* __restrict__ W2, const float* __restrict__ b2,
    const float* __restrict__ fw1, const float* __restrict__ fb1,
    const float* __restrict__ fw2, const float* __restrict__ fb2,
    float* __restrict__ out) {
    __shared__ float acc[128 * 33];
    int b = blockIdx.x, t = threadIdx.x, f = t & 31, g = t >> 5;
    int n0 = b * 128;
    for (int n = g; n < 128; n += 8) {
        int i = n0 + n;
        acc[n * 33 + f] = (i < N_NODES) ? hsc[i * D + f] : 0.f;
    }
    __syncthreads();
    int s0 = bstart[b], s1 = bstart[b + 1];
    int eg = t >> 3, c = t & 7;
    const float4* rowf4 = (const float4*)hsc;
    int e = s0 + eg;
    for (; e + 96 < s1; e += 128) {
        int v0 = ebuf[e], v1 = ebuf[e + 32], v2 = ebuf[e + 64], v3 = ebuf[e + 96];
        float4 r0 = rowf4[(v0 & 0x3FFFF) * 8 + c];
        float4 r1 = rowf4[(v1 & 0x3FFFF) * 8 + c];
        float4 r2 = rowf4[(v2 & 0x3FFFF) * 8 + c];
        float4 r3 = rowf4[(v3 & 0x3FFFF) * 8 + c];
        EDGE_ADD(v0, r0) EDGE_ADD(v1, r1) EDGE_ADD(v2, r2) EDGE_ADD(v3, r3)
    }
    for (; e < s1; e += 32) {
        int v = ebuf[e];
        float4 r = rowf4[(v & 0x3FFFF) * 8 + c];
        EDGE_ADD(v, r)
    }
    __syncthreads();
    float wc1[D], wc2[D];
#pragma unroll
    for (int k = 0; k < D; ++k) { wc1[k] = W1[k * D + f]; wc2[k] = W2[k * D + f]; }
    float b1f = b1[f], b2f = b2[f], g1 = fw1[f], g2 = fw2[f];
    float fb1v = fb1[0], fb2v = fb2[0];
    for (int n = g; n < 128; n += 8) {
        int i = n0 + n;
        if (i >= N_NODES) break;
        float di = dis[i];
        float a1 = 0.f, a2 = 0.f;
#pragma unroll
        for (int k = 0; k < D; ++k) {
            float av = acc[n * 33 + k];
            a1 = fmaf(av, wc1[k], a1);
            a2 = fmaf(av, wc2[k], a2);
        }
        a1 *= di; a2 *= di;
        float v1 = a1 + b1f; v1 = (v1 > 0.f ? v1 : 0.f) * g1;
        float v2 = a2 + b2f; v2 = (v2 > 0.f ? v2 : 0.f) * g2;
#pragma unroll
        for (int o = 16; o > 0; o >>= 1) {
            v1 += __shfl_down(v1, o, 32);
            v2 += __shfl_down(v2, o, 32);
        }
        if (f == 0) {
            out[i * 2] = v1 + fb1v;
            out[i * 2 + 1] = v2 + fb2v;
        }
    }
}

extern "C" void kernel_launch(void* const* d_in, const int* in_sizes, int n_in,
                              void* d_out, int out_size, void* d_ws, size_t ws_size,
                              hipStream_t stream) {
    const float* x       = (const float*)d_in[0];
    const int*   eidx    = (const int*)d_in[1];
    const float* fc1_w   = (const float*)d_in[2];
    const float* fc1_b   = (const float*)d_in[3];
    const float* conv1_w = (const float*)d_in[4];
    const float* conv1_b = (const float*)d_in[5];
    const float* conv2_w = (const float*)d_in[6];
    const float* conv2_b = (const float*)d_in[7];
    const float* c31_w   = (const float*)d_in[8];
    const float* c31_b   = (const float*)d_in[9];
    const float* c32_w   = (const float*)d_in[10];
    const float* c32_b   = (const float*)d_in[11];
    const float* fc21_w  = (const float*)d_in[12];
    const float* fc21_b  = (const float*)d_in[13];
    const float* fc22_w  = (const float*)d_in[14];
    const float* fc22_b  = (const float*)d_in[15];
    float* out = (float*)d_out;

    const int* src = eidx;            // edge_index[0]
    const int* dst = eidx + N_EDGES;  // edge_index[1]

    // ----- workspace layout (int units; xd/HA/HB 16B-aligned) -----
    int*    wsb    = (int*)d_ws;
    int*    ebuf   = wsb;                        // 2,400,000 (persists all layers)
    int*    bstart = wsb + 2400000;              // 1,174
    float*  dis    = (float*)(wsb + 2401184);    // 150,000
    float4* xd     = (float4*)(wsb + 2551184);   // 150,000 float4 (offset %4==0)
    float*  HA     = (float*)(wsb + 3151184);    // 4,800,000
    float*  HB     = (float*)(wsb + 7951184);    // 4,800,000
    int*    cnt    = (int*)HA;                   // 686,792 transient (dead after kB;
                                                 // HA first written by k_lmid)

    const int BLK = 256;

    // ----- bucket-grouped edge buffer + normalization (no CSR fill needed) -----
    kA_hist<<<NCHK, BLK, 0, stream>>>(dst, cnt);
    kS1<<<(NBUCK + 31) / 32, BLK, 0, stream>>>(cnt, bstart);
    k_scan_small<<<1, BLK, 0, stream>>>(bstart, NBUCK);
    kB_scatter<<<NCHK, BLK, 0, stream>>>(src, dst, cnt, bstart, ebuf);
    kD<<<NBUCK, BLK, 0, stream>>>(ebuf, bstart, (const float2*)x, dis, xd);

    // ----- network: one bucket-resident fused kernel per GCN layer -----
    k_l1<<<NBUCK, BLK, 0, stream>>>(ebuf, bstart, xd, fc1_w, fc1_b, conv1_w, conv1_b, HB);
    k_lmid<<<NBUCK, BLK, 0, stream>>>(ebuf, bstart, HB, dis, conv2_w, conv2_b, HA);
    k_lheads<<<NBUCK, BLK, 0, stream>>>(ebuf, bstart, HA, dis, c31_w, c31_b, c32_w, c32_b,
                                        fc21_w, fc21_b, fc22_w, fc22_b, out);
}

// Round 12
// 271.659 us; speedup vs baseline: 5.2429x; 5.2429x over previous
//
#include <hip/hip_runtime.h>

#define N_NODES 150000
#define N_EDGES 2400000
#define D 32
#define NBUCK 1172                 // ceil(N/128)
#define CHUNK 4096
#define NCHK 586                   // ceil(E/CHUNK)
#define CSR_CAP (N_EDGES + 3 * N_NODES + 64)

// ---------- pass A: per-chunk LDS histogram of buckets ----------
__global__ __launch_bounds__(256) void kA_hist(const int* __restrict__ dst,
                                               int* __restrict__ cnt) {
    __shared__ int bins[NBUCK];
    int t = threadIdx.x;
    for (int k = t; k < NBUCK; k += 256) bins[k] = 0;
    __syncthreads();
    int e0 = blockIdx.x * CHUNK;
#pragma unroll
    for (int r = 0; r < CHUNK / 256; ++r) {
        int e = e0 + r * 256 + t;
        if (e < N_EDGES) atomicAdd(&bins[dst[e] >> 7], 1);
    }
    __syncthreads();
    for (int k = t; k < NBUCK; k += 256) cnt[blockIdx.x * NBUCK + k] = bins[k];
}

// ---------- S1: per-bucket exclusive scan over chunks ----------
__global__ __launch_bounds__(256) void kS1(int* __restrict__ cnt, int* __restrict__ bstart) {
    __shared__ int tile[8][33];
    __shared__ int carry[32];
    int t = threadIdx.x;
    int tl = t & 31, tr = t >> 5;
    int b = blockIdx.x * 32 + tl;
    if (t < 32) carry[t] = 0;
    __syncthreads();
    for (int c0 = 0; c0 < NCHK; c0 += 8) {
        int c = c0 + tr;
        int v = (c < NCHK && b < NBUCK) ? cnt[c * NBUCK + b] : 0;
        tile[tr][tl] = v;
        __syncthreads();
        if (t < 32) {
            int s = carry[t];
#pragma unroll
            for (int r = 0; r < 8; ++r) { int x = tile[r][t]; tile[r][t] = s; s += x; }
            carry[t] = s;
        }
        __syncthreads();
        if (c < NCHK && b < NBUCK) cnt[c * NBUCK + b] = tile[tr][tl];
        __syncthreads();
    }
    if (t < 32 && b < NBUCK) bstart[b] = carry[t];
}

// ---------- single-block exclusive scan in place; a[m] = total ----------
__global__ void k_scan_small(int* __restrict__ a, int m) {
    __shared__ int s[256];
    __shared__ int carry;
    int t = threadIdx.x;
    if (t == 0) carry = 0;
    __syncthreads();
    for (int base = 0; base < m; base += 256) {
        int v = (base + t < m) ? a[base + t] : 0;
        s[t] = v;
        __syncthreads();
        for (int off = 1; off < 256; off <<= 1) {
            int add = (t >= off) ? s[t - off] : 0;
            __syncthreads();
            s[t] += add;
            __syncthreads();
        }
        int c0 = carry;
        if (base + t < m) a[base + t] = c0 + s[t] - v;
        int bsum = s[255];
        __syncthreads();
        if (t == 0) carry = c0 + bsum;
        __syncthreads();
    }
    if (t == 0) a[m] = carry;
}

// ---------- pass B: scatter packed edges into bucket-grouped ebuf ----------
__global__ __launch_bounds__(256) void kB_scatter(const int* __restrict__ src,
                                                  const int* __restrict__ dst,
                                                  const int* __restrict__ cnt,
                                                  const int* __restrict__ bstart,
                                                  int* __restrict__ ebuf) {
    __shared__ int lofs[NBUCK];
    int t = threadIdx.x;
    for (int k = t; k < NBUCK; k += 256)
        lofs[k] = bstart[k] + cnt[blockIdx.x * NBUCK + k];
    __syncthreads();
    int e0 = blockIdx.x * CHUNK;
#pragma unroll
    for (int r = 0; r < CHUNK / 256; ++r) {
        int e = e0 + r * 256 + t;
        if (e < N_EDGES) {
            int d = dst[e];
            int p = atomicAdd(&lofs[d >> 7], 1);
            ebuf[p] = src[e] | ((d & 127) << 18);  // src < 2^18
        }
    }
}

// ---------- C1: per-bucket degree histogram -> deg, dis, xd, padded totals ----------
__global__ __launch_bounds__(256) void kC1(const int* __restrict__ ebuf,
                                           const int* __restrict__ bstart,
                                           const float2* __restrict__ x,
                                           int* __restrict__ deg,
                                           float* __restrict__ dis,
                                           float4* __restrict__ xd,
                                           int* __restrict__ pbase) {
    __shared__ int hist[128];
    __shared__ int sc[128];
    int b = blockIdx.x, t = threadIdx.x;
    if (t < 128) hist[t] = 0;
    __syncthreads();
    int s0 = bstart[b], s1 = bstart[b + 1];
    for (int e = s0 + t; e < s1; e += 256) atomicAdd(&hist[ebuf[e] >> 18], 1);
    __syncthreads();
    int i = b * 128 + t;
    if (t < 128) {
        int dv = hist[t];
        if (i < N_NODES) {
            deg[i] = dv;
            float dz = rsqrtf((float)dv + 1.0f);
            dis[i] = dz;
            float2 xv = x[i];
            xd[i] = make_float4(xv.x, xv.y, dz, 0.f);
        } else if (i == N_NODES) {
            xd[i] = make_float4(0.f, 0.f, 0.f, 0.f);
        }
        sc[t] = (i < N_NODES) ? ((dv + 3) & ~3) : 0;  // pad-4
    }
    __syncthreads();
    for (int s = 64; s > 0; s >>= 1) {
        if (t < s) sc[t] += sc[t + s];
        __syncthreads();
    }
    if (t == 0) pbase[b] = sc[0];
}

// ---------- C3: per-bucket CSR fill (pad-4 rows) + irow + slack + zero rows ----------
__global__ __launch_bounds__(256) void kC3(const int* __restrict__ ebuf,
                                           const int* __restrict__ bstart,
                                           const int* __restrict__ deg,
                                           const int* __restrict__ pbase,
                                           int* __restrict__ csr,
                                           int* __restrict__ irow,
                                           float* __restrict__ HA,
                                           float* __restrict__ HB) {
    __shared__ int sc[128];
    __shared__ int loff[128];
    __shared__ int pos[128];
    int b = blockIdx.x, t = threadIdx.x;
    if (b == 0) {
        if (t == 0) irow[N_NODES] = pbase[NBUCK];
        if (t < 64) csr[pbase[NBUCK] + t] = N_NODES;  // slack for 16-wide reads + prefetch
        if (t >= 64 && t < 96) HA[(size_t)N_NODES * D + (t - 64)] = 0.f;   // zero row
        if (t >= 96 && t < 128) HB[(size_t)N_NODES * D + (t - 96)] = 0.f;  // zero row
    }
    int i = b * 128 + t;
    int dv = 0, pad = 0;
    if (t < 128) {
        dv = (i < N_NODES) ? deg[i] : 0;
        pad = (dv + 3) & ~3;
        sc[t] = pad;
        pos[t] = 0;
    }
    __syncthreads();
    for (int off = 1; off < 128; off <<= 1) {
        int add = 0;
        if (t < 128 && t >= off) add = sc[t - off];
        __syncthreads();
        if (t < 128) sc[t] += add;
        __syncthreads();
    }
    int base = pbase[b];
    if (t < 128) {
        loff[t] = sc[t] - pad;  // exclusive prefix
        if (i < N_NODES) irow[i] = base + loff[t];
    }
    __syncthreads();
    int s0 = bstart[b], s1 = bstart[b + 1];
    for (int e = s0 + t; e < s1; e += 256) {
        int v = ebuf[e];
        int dl = v >> 18;
        int p = atomicAdd(&pos[dl], 1);
        csr[base + loff[dl] + p] = v & 0x3FFFF;
    }
    __syncthreads();
    if (t < 128 && i < N_NODES) {
        int st = base + loff[t] + dv, en = base + loff[t] + pad;
        for (int q = st; q < en; ++q) csr[q] = N_NODES;  // pad -> zero row
    }
}

// ---------- layer1 fused with fc1: 2 sequential node-pairs, LDS-staged gather ----------
__global__ __launch_bounds__(256) void k_layer1f(const float4* __restrict__ xd,
                                                 const int* __restrict__ row,
                                                 const int* __restrict__ csr,
                                                 const float* __restrict__ W,   // fc1_w [2][32]
                                                 const float* __restrict__ bf,  // fc1_b
                                                 const float* __restrict__ Wc,  // conv1_w
                                                 const float* __restrict__ bc,  // conv1_b
                                                 float* __restrict__ hout) {
    __shared__ float4 stage[8][2][16];
    __shared__ float arow[16][32];
    int g = threadIdx.x >> 5, l = threadIdx.x & 31, f = l;
    int gg = blockIdx.x * 8 + g;
    if (gg * 4 >= N_NODES) return;  // N % 4 == 0 -> all-or-nothing per group
    float w0 = W[f], w1 = W[D + f], bb = bf[f];
    int half = l >> 4, li = l & 15;
#pragma unroll
    for (int rep = 0; rep < 2; ++rep) {
        int iA = gg * 4 + rep * 2, iB = iA + 1;
        float4 svA = xd[iA], svB = xd[iB];
        float hsA = fmaf(svA.x, w0, fmaf(svA.y, w1, bb)); hsA = hsA > 0.f ? hsA : 0.f;
        float hsB = fmaf(svB.x, w0, fmaf(svB.y, w1, bb)); hsB = hsB > 0.f ? hsB : 0.f;
        float aA = hsA * svA.z, aB = hsB * svB.z;  // self-loop terms
        int rsA = row[iA], mid = row[iB], reB = row[iB + 1];
        int jA = rsA, jB = mid;
        int mye = half ? reB : mid;
        int slot0 = (half ? jB : jA) + li;
        int cs = csr[slot0];
        cs = (slot0 < mye) ? cs : N_NODES;
        while (jA < mid || jB < reB) {
            stage[g][half][li] = xd[cs];  // 32 rows staged in one instruction
            int nslot = (half ? jB : jA) + 16 + li;
            int ncs = csr[nslot];                    // slack-safe read
            ncs = (nslot < mye) ? ncs : N_NODES;     // value sanitize
            if (jA < mid) {
#pragma unroll
                for (int it = 0; it < 4; ++it) {
                    if (jA + it * 4 < mid) {
                        float4 v0 = stage[g][0][it * 4 + 0];
                        float4 v1 = stage[g][0][it * 4 + 1];
                        float4 v2 = stage[g][0][it * 4 + 2];
                        float4 v3 = stage[g][0][it * 4 + 3];
                        float h0 = fmaf(v0.x, w0, fmaf(v0.y, w1, bb)); h0 = h0 > 0.f ? h0 : 0.f;
                        float h1 = fmaf(v1.x, w0, fmaf(v1.y, w1, bb)); h1 = h1 > 0.f ? h1 : 0.f;
                        float h2 = fmaf(v2.x, w0, fmaf(v2.y, w1, bb)); h2 = h2 > 0.f ? h2 : 0.f;
                        float h3 = fmaf(v3.x, w0, fmaf(v3.y, w1, bb)); h3 = h3 > 0.f ? h3 : 0.f;
                        aA = fmaf(h0, v0.z, aA); aA = fmaf(h1, v1.z, aA);
                        aA = fmaf(h2, v2.z, aA); aA = fmaf(h3, v3.z, aA);
                    }
                }
                jA += 16;
            }
            if (jB < reB) {
#pragma unroll
                for (int it = 0; it < 4; ++it) {
                    if (jB + it * 4 < reB) {
                        float4 v0 = stage[g][1][it * 4 + 0];
                        float4 v1 = stage[g][1][it * 4 + 1];
                        float4 v2 = stage[g][1][it * 4 + 2];
                        float4 v3 = stage[g][1][it * 4 + 3];
                        float h0 = fmaf(v0.x, w0, fmaf(v0.y, w1, bb)); h0 = h0 > 0.f ? h0 : 0.f;
                        float h1 = fmaf(v1.x, w0, fmaf(v1.y, w1, bb)); h1 = h1 > 0.f ? h1 : 0.f;
                        float h2 = fmaf(v2.x, w0, fmaf(v2.y, w1, bb)); h2 = h2 > 0.f ? h2 : 0.f;
                        float h3 = fmaf(v3.x, w0, fmaf(v3.y, w1, bb)); h3 = h3 > 0.f ? h3 : 0.f;
                        aB = fmaf(h0, v0.z, aB); aB = fmaf(h1, v1.z, aB);
                        aB = fmaf(h2, v2.z, aB); aB = fmaf(h3, v3.z, aB);
                    }
                }
                jB += 16;
            }
            cs = ncs;
        }
        aA *= svA.z; aB *= svB.z;
        arow[g * 2][f] = aA;
        arow[g * 2 + 1][f] = aB;
        float accA = 0.f, accB = 0.f;
#pragma unroll
        for (int q = 0; q < 8; ++q) {
            float4 qa = ((const float4*)arow[g * 2])[q];
            float4 qb = ((const float4*)arow[g * 2 + 1])[q];
            float wq0 = Wc[(4 * q + 0) * D + f], wq1 = Wc[(4 * q + 1) * D + f];
            float wq2 = Wc[(4 * q + 2) * D + f], wq3 = Wc[(4 * q + 3) * D + f];
            accA = fmaf(qa.x, wq0, fmaf(qa.y, wq1, fmaf(qa.z, wq2, fmaf(qa.w, wq3, accA))));
            accB = fmaf(qb.x, wq0, fmaf(qb.y, wq1, fmaf(qb.z, wq2, fmaf(qb.w, wq3, accB))));
        }
        float bcf = bc[f];
        float vA = accA + bcf; vA = vA > 0.f ? vA : 0.f;
        float vB = accB + bcf; vB = vB > 0.f ? vB : 0.f;
        hout[iA * D + f] = vA * svA.z;
        hout[iB * D + f] = vB * svB.z;
    }
}

// ---------- fused layer: 2 sequential node-pairs, 8-loads-in-flight gather ----------
__global__ __launch_bounds__(256) void k_layer(const float* __restrict__ hsc,
                                               const int* __restrict__ row,
                                               const int* __restrict__ csr,
                                               const float* __restrict__ dis,
                                               const float* __restrict__ W,
                                               const float* __restrict__ b,
                                               float* __restrict__ hout) {
    __shared__ float arow[16][32];
    int g = threadIdx.x >> 5, l = threadIdx.x & 31, f = l;
    int gg = blockIdx.x * 8 + g;
    if (gg * 4 >= N_NODES) return;
    int c = l & 7, l16 = l & 15, sub = l >> 3;
    const float4* rowf4 = (const float4*)hsc;
#pragma unroll
    for (int rep = 0; rep < 2; ++rep) {
        int iA = gg * 4 + rep * 2, iB = iA + 1;
        int rsA = row[iA], mid = row[iB], reB = row[iB + 1];
        float4 aA = make_float4(0.f, 0.f, 0.f, 0.f);
        float4 aB = make_float4(0.f, 0.f, 0.f, 0.f);
        int jA = rsA, jB = mid;
        int csA = csr[jA + l16], csB = csr[jB + l16];
        while (jA < mid && jB < reB) {
            int nA = csr[jA + 16 + l16], nB = csr[jB + 16 + l16];
            float4 vA[4], vB[4];
#pragma unroll
            for (int it = 0; it < 4; ++it)
                if (jA + it * 4 < mid) { int s = __shfl(csA, it * 4 + sub, 32); vA[it] = rowf4[s * 8 + c]; }
#pragma unroll
            for (int it = 0; it < 4; ++it)
                if (jB + it * 4 < reB) { int s = __shfl(csB, it * 4 + sub, 32); vB[it] = rowf4[s * 8 + c]; }
#pragma unroll
            for (int it = 0; it < 4; ++it) {
                if (jA + it * 4 < mid) { aA.x += vA[it].x; aA.y += vA[it].y; aA.z += vA[it].z; aA.w += vA[it].w; }
                if (jB + it * 4 < reB) { aB.x += vB[it].x; aB.y += vB[it].y; aB.z += vB[it].z; aB.w += vB[it].w; }
            }
            csA = nA; csB = nB; jA += 16; jB += 16;
        }
        while (jA < mid) {
            int nA = csr[jA + 16 + l16];
            float4 vA[4];
#pragma unroll
            for (int it = 0; it < 4; ++it)
                if (jA + it * 4 < mid) { int s = __shfl(csA, it * 4 + sub, 32); vA[it] = rowf4[s * 8 + c]; }
#pragma unroll
            for (int it = 0; it < 4; ++it)
                if (jA + it * 4 < mid) { aA.x += vA[it].x; aA.y += vA[it].y; aA.z += vA[it].z; aA.w += vA[it].w; }
            csA = nA; jA += 16;
        }
        while (jB < reB) {
            int nB = csr[jB + 16 + l16];
            float4 vB[4];
#pragma unroll
            for (int it = 0; it < 4; ++it)
                if (jB + it * 4 < reB) { int s = __shfl(csB, it * 4 + sub, 32); vB[it] = rowf4[s * 8 + c]; }
#pragma unroll
            for (int it = 0; it < 4; ++it)
                if (jB + it * 4 < reB) { aB.x += vB[it].x; aB.y += vB[it].y; aB.z += vB[it].z; aB.w += vB[it].w; }
            csB = nB; jB += 16;
        }
        aA.x += __shfl_xor(aA.x, 8, 32);  aA.y += __shfl_xor(aA.y, 8, 32);
        aA.z += __shfl_xor(aA.z, 8, 32);  aA.w += __shfl_xor(aA.w, 8, 32);
        aA.x += __shfl_xor(aA.x, 16, 32); aA.y += __shfl_xor(aA.y, 16, 32);
        aA.z += __shfl_xor(aA.z, 16, 32); aA.w += __shfl_xor(aA.w, 16, 32);
        aB.x += __shfl_xor(aB.x, 8, 32);  aB.y += __shfl_xor(aB.y, 8, 32);
        aB.z += __shfl_xor(aB.z, 8, 32);  aB.w += __shfl_xor(aB.w, 8, 32);
        aB.x += __shfl_xor(aB.x, 16, 32); aB.y += __shfl_xor(aB.y, 16, 32);
        aB.z += __shfl_xor(aB.z, 16, 32); aB.w += __shfl_xor(aB.w, 16, 32);
        float4 svA = rowf4[iA * 8 + c], svB = rowf4[iB * 8 + c];
        float diA = dis[iA], diB = dis[iB];
        aA.x = (aA.x + svA.x) * diA; aA.y = (aA.y + svA.y) * diA;
        aA.z = (aA.z + svA.z) * diA; aA.w = (aA.w + svA.w) * diA;
        aB.x = (aB.x + svB.x) * diB; aB.y = (aB.y + svB.y) * diB;
        aB.z = (aB.z + svB.z) * diB; aB.w = (aB.w + svB.w) * diB;
        if (l < 8) ((float4*)arow[g * 2])[l] = aA;
        else if (l < 16) ((float4*)arow[g * 2 + 1])[l - 8] = aB;
        float accA = 0.f, accB = 0.f;
#pragma unroll
        for (int q = 0; q < 8; ++q) {
            float4 qa = ((const float4*)arow[g * 2])[q];
            float4 qb = ((const float4*)arow[g * 2 + 1])[q];
            float wq0 = W[(4 * q + 0) * D + f], wq1 = W[(4 * q + 1) * D + f];
            float wq2 = W[(4 * q + 2) * D + f], wq3 = W[(4 * q + 3) * D + f];
            accA = fmaf(qa.x, wq0, fmaf(qa.y, wq1, fmaf(qa.z, wq2, fmaf(qa.w, wq3, accA))));
            accB = fmaf(qb.x, wq0, fmaf(qb.y, wq1, fmaf(qb.z, wq2, fmaf(qb.w, wq3, accB))));
        }
        float bb = b[f];
        float vA_ = accA + bb; vA_ = vA_ > 0.f ? vA_ : 0.f;
        float vB_ = accB + bb; vB_ = vB_ > 0.f ? vB_ : 0.f;
        hout[iA * D + f] = vA_ * diA;
        hout[iB * D + f] = vB_ * diB;
    }
}

// ---------- heads: 2 sequential node-pairs, dual transform + 32->1 dots ----------
__global__ __launch_bounds__(256) void k_heads(
    const float* __restrict__ hsc, const int* __restrict__ row,
    const int* __restrict__ csr, const float* __restrict__ dis,
    const float* __restrict__ W1, const float* __restrict__ b1,
    const float* __restrict__ W2, const float* __restrict__ b2,
    const float* __restrict__ fw1, const float* __restrict__ fb1,
    const float* __restrict__ fw2, const float* __restrict__ fb2,
    float* __restrict__ out) {
    __shared__ float arow[16][32];
    int g = threadIdx.x >> 5, l = threadIdx.x & 31, f = l;
    int gg = blockIdx.x * 8 + g;
    if (gg * 4 >= N_NODES) return;
    int c = l & 7, l16 = l & 15, sub = l >> 3;
    const float4* rowf4 = (const float4*)hsc;
#pragma unroll
    for (int rep = 0; rep < 2; ++rep) {
        int iA = gg * 4 + rep * 2, iB = iA + 1;
        int rsA = row[iA], mid = row[iB], reB = row[iB + 1];
        float4 aA = make_float4(0.f, 0.f, 0.f, 0.f);
        float4 aB = make_float4(0.f, 0.f, 0.f, 0.f);
        int jA = rsA, jB = mid;
        int csA = csr[jA + l16], csB = csr[jB + l16];
        while (jA < mid && jB < reB) {
            int nA = csr[jA + 16 + l16], nB = csr[jB + 16 + l16];
            float4 vA[4], vB[4];
#pragma unroll
            for (int it = 0; it < 4; ++it)
                if (jA + it * 4 < mid) { int s = __shfl(csA, it * 4 + sub, 32); vA[it] = rowf4[s * 8 + c]; }
#pragma unroll
            for (int it = 0; it < 4; ++it)
                if (jB + it * 4 < reB) { int s = __shfl(csB, it * 4 + sub, 32); vB[it] = rowf4[s * 8 + c]; }
#pragma unroll
            for (int it = 0; it < 4; ++it) {
                if (jA + it * 4 < mid) { aA.x += vA[it].x; aA.y += vA[it].y; aA.z += vA[it].z; aA.w += vA[it].w; }
                if (jB + it * 4 < reB) { aB.x += vB[it].x; aB.y += vB[it].y; aB.z += vB[it].z; aB.w += vB[it].w; }
            }
            csA = nA; csB = nB; jA += 16; jB += 16;
        }
        while (jA < mid) {
            int nA = csr[jA + 16 + l16];
            float4 vA[4];
#pragma unroll
            for (int it = 0; it < 4; ++it)
                if (jA + it * 4 < mid) { int s = __shfl(csA, it * 4 + sub, 32); vA[it] = rowf4[s * 8 + c]; }
#pragma unroll
            for (int it = 0; it < 4; ++it)
                if (jA + it * 4 < mid) { aA.x += vA[it].x; aA.y += vA[it].y; aA.z += vA[it].z; aA.w += vA[it].w; }
            csA = nA; jA += 16;
        }
        while (jB < reB) {
            int nB = csr[jB + 16 + l16];
            float4 vB[4];
#pragma unroll
            for (int it = 0; it < 4; ++it)
                if (jB + it * 4 < reB) { int s = __shfl(csB, it * 4 + sub, 32); vB[it] = rowf4[s * 8 + c]; }
#pragma unroll
            for (int it = 0; it < 4; ++it)
                if (jB + it * 4 < reB) { aB.x += vB[it].x; aB.y += vB[it].y; aB.z += vB[it].z; aB.w += vB[it].w; }
            csB = nB; jB += 16;
        }
        aA.x += __shfl_xor(aA.x, 8, 32);  aA.y += __shfl_xor(aA.y, 8, 32);
        aA.z += __shfl_xor(aA.z, 8, 32);  aA.w += __shfl_xor(aA.w, 8, 32);
        aA.x += __shfl_xor(aA.x, 16, 32); aA.y += __shfl_xor(aA.y, 16, 32);
        aA.z += __shfl_xor(aA.z, 16, 32); aA.w += __shfl_xor(aA.w, 16, 32);
        aB.x += __shfl_xor(aB.x, 8, 32);  aB.y += __shfl_xor(aB.y, 8, 32);
        aB.z += __shfl_xor(aB.z, 8, 32);  aB.w += __shfl_xor(aB.w, 8, 32);
        aB.x += __shfl_xor(aB.x, 16, 32); aB.y += __shfl_xor(aB.y, 16, 32);
        aB.z += __shfl_xor(aB.z, 16, 32); aB.w += __shfl_xor(aB.w, 16, 32);
        float4 svA = rowf4[iA * 8 + c], svB = rowf4[iB * 8 + c];
        float diA = dis[iA], diB = dis[iB];
        aA.x = (aA.x + svA.x) * diA; aA.y = (aA.y + svA.y) * diA;
        aA.z = (aA.z + svA.z) * diA; aA.w = (aA.w + svA.w) * diA;
        aB.x = (aB.x + svB.x) * diB; aB.y = (aB.y + svB.y) * diB;
        aB.z = (aB.z + svB.z) * diB; aB.w = (aB.w + svB.w) * diB;
        if (l < 8) ((float4*)arow[g * 2])[l] = aA;
        else if (l < 16) ((float4*)arow[g * 2 + 1])[l - 8] = aB;
        float a1A = 0.f, a2A = 0.f, a1B = 0.f, a2B = 0.f;
#pragma unroll
        for (int q = 0; q < 8; ++q) {
            float4 qa = ((const float4*)arow[g * 2])[q];
            float4 qb = ((const float4*)arow[g * 2 + 1])[q];
            float u0 = W1[(4 * q + 0) * D + f], u1 = W1[(4 * q + 1) * D + f];
            float u2 = W1[(4 * q + 2) * D + f], u3 = W1[(4 * q + 3) * D + f];
            float t0 = W2[(4 * q + 0) * D + f], t1 = W2[(4 * q + 1) * D + f];
            float t2 = W2[(4 * q + 2) * D + f], t3 = W2[(4 * q + 3) * D + f];
            a1A = fmaf(qa.x, u0, fmaf(qa.y, u1, fmaf(qa.z, u2, fmaf(qa.w, u3, a1A))));
            a2A = fmaf(qa.x, t0, fmaf(qa.y, t1, fmaf(qa.z, t2, fmaf(qa.w, t3, a2A))));
            a1B = fmaf(qb.x, u0, fmaf(qb.y, u1, fmaf(qb.z, u2, fmaf(qb.w, u3, a1B))));
            a2B = fmaf(qb.x, t0, fmaf(qb.y, t1, fmaf(qb.z, t2, fmaf(qb.w, t3, a2B))));
        }
        float v1A = a1A + b1[f]; v1A = (v1A > 0.f ? v1A : 0.f) * fw1[f];
        float v2A = a2A + b2[f]; v2A = (v2A > 0.f ? v2A : 0.f) * fw2[f];
        float v1B = a1B + b1[f]; v1B = (v1B > 0.f ? v1B : 0.f) * fw1[f];
        float v2B = a2B + b2[f]; v2B = (v2B > 0.f ? v2B : 0.f) * fw2[f];
#pragma unroll
        for (int o = 16; o > 0; o >>= 1) {
            v1A += __shfl_down(v1A, o, 32);
            v2A += __shfl_down(v2A, o, 32);
            v1B += __shfl_down(v1B, o, 32);
            v2B += __shfl_down(v2B, o, 32);
        }
        if (l == 0) {
            float4 o4 = make_float4(v1A + fb1[0], v2A + fb2[0], v1B + fb1[0], v2B + fb2[0]);
            *(float4*)&out[iA * 2] = o4;  // iA even -> 16B aligned
        }
    }
}

extern "C" void kernel_launch(void* const* d_in, const int* in_sizes, int n_in,
                              void* d_out, int out_size, void* d_ws, size_t ws_size,
                              hipStream_t stream) {
    const float* x       = (const float*)d_in[0];
    const int*   eidx    = (const int*)d_in[1];
    const float* fc1_w   = (const float*)d_in[2];
    const float* fc1_b   = (const float*)d_in[3];
    const float* conv1_w = (const float*)d_in[4];
    const float* conv1_b = (const float*)d_in[5];
    const float* conv2_w = (const float*)d_in[6];
    const float* conv2_b = (const float*)d_in[7];
    const float* c31_w   = (const float*)d_in[8];
    const float* c31_b   = (const float*)d_in[9];
    const float* c32_w   = (const float*)d_in[10];
    const float* c32_b   = (const float*)d_in[11];
    const float* fc21_w  = (const float*)d_in[12];
    const float* fc21_b  = (const float*)d_in[13];
    const float* fc22_w  = (const float*)d_in[14];
    const float* fc22_b  = (const float*)d_in[15];
    float* out = (float*)d_out;

    const int* src = eidx;            // edge_index[0]
    const int* dst = eidx + N_EDGES;  // edge_index[1]

    // ----- workspace layout (int units; 16B alignment preserved) -----
    int*   wsb    = (int*)d_ws;
    int*   csr    = wsb;                        // CSR_CAP
    int*   irow   = wsb + 2850064;              // 150,004
    int*   bstart = wsb + 3000068;              // 1,174
    int*   pbase  = wsb + 3001242;              // 1,174
    float* dis    = (float*)(wsb + 3002416);    // 150,000
    float* HA     = (float*)(wsb + 3152416);    // 4,800,032 floats
    float* HB     = (float*)(wsb + 7952448);    // 4,800,032 floats
    // transient aliases inside HA (dead before k_layer writes HA):
    int*    cnt  = (int*)HA;                    // 686,792
    int*    ebuf = (int*)HA + 700000;           // 2,400,000
    float4* xd   = (float4*)((int*)HA + 3100016);  // (N+1) float4
    // deg aliases HB low (dead before k_layer1f writes HB):
    int*    deg  = (int*)HB;                    // 150,000

    const int BLK = 256;
    const int gL  = (N_NODES + 31) / 32;        // 4688 blocks, 32 nodes each

    // ----- CSR build (no global atomics) -----
    kA_hist<<<NCHK, BLK, 0, stream>>>(dst, cnt);
    kS1<<<(NBUCK + 31) / 32, BLK, 0, stream>>>(cnt, bstart);
    k_scan_small<<<1, BLK, 0, stream>>>(bstart, NBUCK);
    kB_scatter<<<NCHK, BLK, 0, stream>>>(src, dst, cnt, bstart, ebuf);
    kC1<<<NBUCK, BLK, 0, stream>>>(ebuf, bstart, (const float2*)x, deg, dis, xd, pbase);
    k_scan_small<<<1, BLK, 0, stream>>>(pbase, NBUCK);
    kC3<<<NBUCK, BLK, 0, stream>>>(ebuf, bstart, deg, pbase, csr, irow, HA, HB);

    // ----- network -----
    k_layer1f<<<gL, BLK, 0, stream>>>(xd, irow, csr, fc1_w, fc1_b, conv1_w, conv1_b, HB);
    k_layer<<<gL, BLK, 0, stream>>>(HB, irow, csr, dis, conv2_w, conv2_b, HA);
    k_heads<<<gL, BLK, 0, stream>>>(HA, irow, csr, dis, c31_w, c31_b, c32_w, c32_b,
                                    fc21_w, fc21_b, fc22_w, fc22_b, out);
}

// Round 13
// 251.653 us; speedup vs baseline: 5.6597x; 1.0795x over previous
//
#include <hip/hip_runtime.h>

#define N_NODES 150000
#define N_EDGES 2400000
#define D 32
#define NBUCK 1172                 // ceil(N/128)
#define CHUNK 4096
#define NCHK 586                   // ceil(E/CHUNK)
#define CSR_CAP (N_EDGES + 3 * N_NODES + 64)

// ---------- pass A: per-chunk LDS histogram of buckets ----------
__global__ __launch_bounds__(256) void kA_hist(const int* __restrict__ dst,
                                               int* __restrict__ cnt) {
    __shared__ int bins[NBUCK];
    int t = threadIdx.x;
    for (int k = t; k < NBUCK; k += 256) bins[k] = 0;
    __syncthreads();
    int e0 = blockIdx.x * CHUNK;
#pragma unroll
    for (int r = 0; r < CHUNK / 256; ++r) {
        int e = e0 + r * 256 + t;
        if (e < N_EDGES) atomicAdd(&bins[dst[e] >> 7], 1);
    }
    __syncthreads();
    for (int k = t; k < NBUCK; k += 256) cnt[blockIdx.x * NBUCK + k] = bins[k];
}

// ---------- S1: per-bucket exclusive scan over chunks ----------
__global__ __launch_bounds__(256) void kS1(int* __restrict__ cnt, int* __restrict__ bstart) {
    __shared__ int tile[8][33];
    __shared__ int carry[32];
    int t = threadIdx.x;
    int tl = t & 31, tr = t >> 5;
    int b = blockIdx.x * 32 + tl;
    if (t < 32) carry[t] = 0;
    __syncthreads();
    for (int c0 = 0; c0 < NCHK; c0 += 8) {
        int c = c0 + tr;
        int v = (c < NCHK && b < NBUCK) ? cnt[c * NBUCK + b] : 0;
        tile[tr][tl] = v;
        __syncthreads();
        if (t < 32) {
            int s = carry[t];
#pragma unroll
            for (int r = 0; r < 8; ++r) { int x = tile[r][t]; tile[r][t] = s; s += x; }
            carry[t] = s;
        }
        __syncthreads();
        if (c < NCHK && b < NBUCK) cnt[c * NBUCK + b] = tile[tr][tl];
        __syncthreads();
    }
    if (t < 32 && b < NBUCK) bstart[b] = carry[t];
}

// ---------- single-block exclusive scan in place; a[m] = total ----------
__global__ void k_scan_small(int* __restrict__ a, int m) {
    __shared__ int s[256];
    __shared__ int carry;
    int t = threadIdx.x;
    if (t == 0) carry = 0;
    __syncthreads();
    for (int base = 0; base < m; base += 256) {
        int v = (base + t < m) ? a[base + t] : 0;
        s[t] = v;
        __syncthreads();
        for (int off = 1; off < 256; off <<= 1) {
            int add = (t >= off) ? s[t - off] : 0;
            __syncthreads();
            s[t] += add;
            __syncthreads();
        }
        int c0 = carry;
        if (base + t < m) a[base + t] = c0 + s[t] - v;
        int bsum = s[255];
        __syncthreads();
        if (t == 0) carry = c0 + bsum;
        __syncthreads();
    }
    if (t == 0) a[m] = carry;
}

// ---------- pass B: scatter packed edges into bucket-grouped ebuf ----------
__global__ __launch_bounds__(256) void kB_scatter(const int* __restrict__ src,
                                                  const int* __restrict__ dst,
                                                  const int* __restrict__ cnt,
                                                  const int* __restrict__ bstart,
                                                  int* __restrict__ ebuf) {
    __shared__ int lofs[NBUCK];
    int t = threadIdx.x;
    for (int k = t; k < NBUCK; k += 256)
        lofs[k] = bstart[k] + cnt[blockIdx.x * NBUCK + k];
    __syncthreads();
    int e0 = blockIdx.x * CHUNK;
#pragma unroll
    for (int r = 0; r < CHUNK / 256; ++r) {
        int e = e0 + r * 256 + t;
        if (e < N_EDGES) {
            int d = dst[e];
            int p = atomicAdd(&lofs[d >> 7], 1);
            ebuf[p] = src[e] | ((d & 127) << 18);  // src < 2^18
        }
    }
}

// ---------- C1: per-bucket degree histogram -> deg, dis, xd, padded totals ----------
__global__ __launch_bounds__(256) void kC1(const int* __restrict__ ebuf,
                                           const int* __restrict__ bstart,
                                           const float2* __restrict__ x,
                                           int* __restrict__ deg,
                                           float* __restrict__ dis,
                                           float4* __restrict__ xd,
                                           int* __restrict__ pbase) {
    __shared__ int hist[128];
    __shared__ int sc[128];
    int b = blockIdx.x, t = threadIdx.x;
    if (t < 128) hist[t] = 0;
    __syncthreads();
    int s0 = bstart[b], s1 = bstart[b + 1];
    for (int e = s0 + t; e < s1; e += 256) atomicAdd(&hist[ebuf[e] >> 18], 1);
    __syncthreads();
    int i = b * 128 + t;
    if (t < 128) {
        int dv = hist[t];
        if (i < N_NODES) {
            deg[i] = dv;
            float dz = rsqrtf((float)dv + 1.0f);
            dis[i] = dz;
            float2 xv = x[i];
            xd[i] = make_float4(xv.x, xv.y, dz, 0.f);
        } else if (i == N_NODES) {
            xd[i] = make_float4(0.f, 0.f, 0.f, 0.f);
        }
        sc[t] = (i < N_NODES) ? ((dv + 3) & ~3) : 0;  // pad-4
    }
    __syncthreads();
    for (int s = 64; s > 0; s >>= 1) {
        if (t < s) sc[t] += sc[t + s];
        __syncthreads();
    }
    if (t == 0) pbase[b] = sc[0];
}

// ---------- C3: per-bucket CSR fill (pad-4 rows) + irow + slack + zero rows ----------
__global__ __launch_bounds__(256) void kC3(const int* __restrict__ ebuf,
                                           const int* __restrict__ bstart,
                                           const int* __restrict__ deg,
                                           const int* __restrict__ pbase,
                                           int* __restrict__ csr,
                                           int* __restrict__ irow,
                                           float* __restrict__ HA,
                                           float* __restrict__ HB) {
    __shared__ int sc[128];
    __shared__ int loff[128];
    __shared__ int pos[128];
    int b = blockIdx.x, t = threadIdx.x;
    if (b == 0) {
        if (t == 0) irow[N_NODES] = pbase[NBUCK];
        if (t < 64) csr[pbase[NBUCK] + t] = N_NODES;  // slack for 16-wide reads + prefetch
        if (t >= 64 && t < 96) HA[(size_t)N_NODES * D + (t - 64)] = 0.f;   // zero row
        if (t >= 96 && t < 128) HB[(size_t)N_NODES * D + (t - 96)] = 0.f;  // zero row
    }
    int i = b * 128 + t;
    int dv = 0, pad = 0;
    if (t < 128) {
        dv = (i < N_NODES) ? deg[i] : 0;
        pad = (dv + 3) & ~3;
        sc[t] = pad;
        pos[t] = 0;
    }
    __syncthreads();
    for (int off = 1; off < 128; off <<= 1) {
        int add = 0;
        if (t < 128 && t >= off) add = sc[t - off];
        __syncthreads();
        if (t < 128) sc[t] += add;
        __syncthreads();
    }
    int base = pbase[b];
    if (t < 128) {
        loff[t] = sc[t] - pad;  // exclusive prefix
        if (i < N_NODES) irow[i] = base + loff[t];
    }
    __syncthreads();
    int s0 = bstart[b], s1 = bstart[b + 1];
    for (int e = s0 + t; e < s1; e += 256) {
        int v = ebuf[e];
        int dl = v >> 18;
        int p = atomicAdd(&pos[dl], 1);
        csr[base + loff[dl] + p] = v & 0x3FFFF;
    }
    __syncthreads();
    if (t < 128 && i < N_NODES) {
        int st = base + loff[t] + dv, en = base + loff[t] + pad;
        for (int q = st; q < en; ++q) csr[q] = N_NODES;  // pad -> zero row
    }
}

// ---------- layer1 fused with fc1: 2-node LDS-staged gather + broadcast MLP ----------
__global__ __launch_bounds__(256) void k_layer1f(const float4* __restrict__ xd,
                                                 const int* __restrict__ row,
                                                 const int* __restrict__ csr,
                                                 const float* __restrict__ W,   // fc1_w [2][32]
                                                 const float* __restrict__ bf,  // fc1_b
                                                 const float* __restrict__ Wc,  // conv1_w
                                                 const float* __restrict__ bc,  // conv1_b
                                                 float* __restrict__ hout) {
    __shared__ float4 stage[8][2][16];
    __shared__ float arow[16][32];
    int g = threadIdx.x >> 5, l = threadIdx.x & 31, f = l;
    int gg = blockIdx.x * 8 + g;
    int iA = gg * 2, iB = iA + 1;  // 9375*8*2 == 150000, exact grid
    float w0 = W[f], w1 = W[D + f], bb = bf[f];
    float4 svA = xd[iA], svB = xd[iB];
    float hsA = fmaf(svA.x, w0, fmaf(svA.y, w1, bb)); hsA = hsA > 0.f ? hsA : 0.f;
    float hsB = fmaf(svB.x, w0, fmaf(svB.y, w1, bb)); hsB = hsB > 0.f ? hsB : 0.f;
    float aA = hsA * svA.z, aB = hsB * svB.z;  // self-loop terms
    int rsA = row[iA], mid = row[iB], reB = row[iB + 1];
    int jA = rsA, jB = mid;
    int half = l >> 4, li = l & 15;
    int mye = half ? reB : mid;
    int slot0 = (half ? jB : jA) + li;
    int cs = csr[slot0];
    cs = (slot0 < mye) ? cs : N_NODES;
    while (jA < mid || jB < reB) {
        stage[g][half][li] = xd[cs];  // 32 rows staged in one instruction
        int nslot = (half ? jB : jA) + 16 + li;
        int ncs = csr[nslot];                    // slack-safe read
        ncs = (nslot < mye) ? ncs : N_NODES;     // value sanitize
        if (jA < mid) {
#pragma unroll
            for (int it = 0; it < 4; ++it) {
                if (jA + it * 4 < mid) {
                    float4 v0 = stage[g][0][it * 4 + 0];
                    float4 v1 = stage[g][0][it * 4 + 1];
                    float4 v2 = stage[g][0][it * 4 + 2];
                    float4 v3 = stage[g][0][it * 4 + 3];
                    float h0 = fmaf(v0.x, w0, fmaf(v0.y, w1, bb)); h0 = h0 > 0.f ? h0 : 0.f;
                    float h1 = fmaf(v1.x, w0, fmaf(v1.y, w1, bb)); h1 = h1 > 0.f ? h1 : 0.f;
                    float h2 = fmaf(v2.x, w0, fmaf(v2.y, w1, bb)); h2 = h2 > 0.f ? h2 : 0.f;
                    float h3 = fmaf(v3.x, w0, fmaf(v3.y, w1, bb)); h3 = h3 > 0.f ? h3 : 0.f;
                    aA = fmaf(h0, v0.z, aA); aA = fmaf(h1, v1.z, aA);
                    aA = fmaf(h2, v2.z, aA); aA = fmaf(h3, v3.z, aA);
                }
            }
            jA += 16;
        }
        if (jB < reB) {
#pragma unroll
            for (int it = 0; it < 4; ++it) {
                if (jB + it * 4 < reB) {
                    float4 v0 = stage[g][1][it * 4 + 0];
                    float4 v1 = stage[g][1][it * 4 + 1];
                    float4 v2 = stage[g][1][it * 4 + 2];
                    float4 v3 = stage[g][1][it * 4 + 3];
                    float h0 = fmaf(v0.x, w0, fmaf(v0.y, w1, bb)); h0 = h0 > 0.f ? h0 : 0.f;
                    float h1 = fmaf(v1.x, w0, fmaf(v1.y, w1, bb)); h1 = h1 > 0.f ? h1 : 0.f;
                    float h2 = fmaf(v2.x, w0, fmaf(v2.y, w1, bb)); h2 = h2 > 0.f ? h2 : 0.f;
                    float h3 = fmaf(v3.x, w0, fmaf(v3.y, w1, bb)); h3 = h3 > 0.f ? h3 : 0.f;
                    aB = fmaf(h0, v0.z, aB); aB = fmaf(h1, v1.z, aB);
                    aB = fmaf(h2, v2.z, aB); aB = fmaf(h3, v3.z, aB);
                }
            }
            jB += 16;
        }
        cs = ncs;
    }
    aA *= svA.z; aB *= svB.z;
    arow[g * 2][f] = aA;
    arow[g * 2 + 1][f] = aB;
    float accA = 0.f, accB = 0.f;
#pragma unroll
    for (int q = 0; q < 8; ++q) {
        float4 qa = ((const float4*)arow[g * 2])[q];
        float4 qb = ((const float4*)arow[g * 2 + 1])[q];
        float wq0 = Wc[(4 * q + 0) * D + f], wq1 = Wc[(4 * q + 1) * D + f];
        float wq2 = Wc[(4 * q + 2) * D + f], wq3 = Wc[(4 * q + 3) * D + f];
        accA = fmaf(qa.x, wq0, fmaf(qa.y, wq1, fmaf(qa.z, wq2, fmaf(qa.w, wq3, accA))));
        accB = fmaf(qb.x, wq0, fmaf(qb.y, wq1, fmaf(qb.z, wq2, fmaf(qb.w, wq3, accB))));
    }
    float bcf = bc[f];
    float vA = accA + bcf; vA = vA > 0.f ? vA : 0.f;
    float vB = accB + bcf; vB = vB > 0.f ? vB : 0.f;
    hout[iA * D + f] = vA * svA.z;
    hout[iB * D + f] = vB * svB.z;
}

// ---------- fused layer: 2-node batched gather (8 loads in flight) + transform ----------
__global__ __launch_bounds__(256) void k_layer(const float* __restrict__ hsc,
                                               const int* __restrict__ row,
                                               const int* __restrict__ csr,
                                               const float* __restrict__ dis,
                                               const float* __restrict__ W,
                                               const float* __restrict__ b,
                                               float* __restrict__ hout) {
    __shared__ float arow[16][32];
    int g = threadIdx.x >> 5, l = threadIdx.x & 31, f = l;
    int gg = blockIdx.x * 8 + g;
    int iA = gg * 2, iB = iA + 1;  // N even; exact grid
    float wcol[D];
#pragma unroll
    for (int k = 0; k < D; ++k) wcol[k] = W[k * D + f];
    int c = l & 7, l16 = l & 15, sub = l >> 3;
    const float4* rowf4 = (const float4*)hsc;
    int rsA = row[iA], mid = row[iB], reB = row[iB + 1];
    float4 aA = make_float4(0.f, 0.f, 0.f, 0.f);
    float4 aB = make_float4(0.f, 0.f, 0.f, 0.f);
    int jA = rsA, jB = mid;
    int csA = csr[jA + l16], csB = csr[jB + l16];
    while (jA < mid && jB < reB) {
        int nA = csr[jA + 16 + l16], nB = csr[jB + 16 + l16];
        float4 vA[4], vB[4];
#pragma unroll
        for (int it = 0; it < 4; ++it)
            if (jA + it * 4 < mid) { int s = __shfl(csA, it * 4 + sub, 32); vA[it] = rowf4[s * 8 + c]; }
#pragma unroll
        for (int it = 0; it < 4; ++it)
            if (jB + it * 4 < reB) { int s = __shfl(csB, it * 4 + sub, 32); vB[it] = rowf4[s * 8 + c]; }
#pragma unroll
        for (int it = 0; it < 4; ++it) {
            if (jA + it * 4 < mid) { aA.x += vA[it].x; aA.y += vA[it].y; aA.z += vA[it].z; aA.w += vA[it].w; }
            if (jB + it * 4 < reB) { aB.x += vB[it].x; aB.y += vB[it].y; aB.z += vB[it].z; aB.w += vB[it].w; }
        }
        csA = nA; csB = nB; jA += 16; jB += 16;
    }
    while (jA < mid) {
        int nA = csr[jA + 16 + l16];
        float4 vA[4];
#pragma unroll
        for (int it = 0; it < 4; ++it)
            if (jA + it * 4 < mid) { int s = __shfl(csA, it * 4 + sub, 32); vA[it] = rowf4[s * 8 + c]; }
#pragma unroll
        for (int it = 0; it < 4; ++it)
            if (jA + it * 4 < mid) { aA.x += vA[it].x; aA.y += vA[it].y; aA.z += vA[it].z; aA.w += vA[it].w; }
        csA = nA; jA += 16;
    }
    while (jB < reB) {
        int nB = csr[jB + 16 + l16];
        float4 vB[4];
#pragma unroll
        for (int it = 0; it < 4; ++it)
            if (jB + it * 4 < reB) { int s = __shfl(csB, it * 4 + sub, 32); vB[it] = rowf4[s * 8 + c]; }
#pragma unroll
        for (int it = 0; it < 4; ++it)
            if (jB + it * 4 < reB) { aB.x += vB[it].x; aB.y += vB[it].y; aB.z += vB[it].z; aB.w += vB[it].w; }
        csB = nB; jB += 16;
    }
    aA.x += __shfl_xor(aA.x, 8, 32);  aA.y += __shfl_xor(aA.y, 8, 32);
    aA.z += __shfl_xor(aA.z, 8, 32);  aA.w += __shfl_xor(aA.w, 8, 32);
    aA.x += __shfl_xor(aA.x, 16, 32); aA.y += __shfl_xor(aA.y, 16, 32);
    aA.z += __shfl_xor(aA.z, 16, 32); aA.w += __shfl_xor(aA.w, 16, 32);
    aB.x += __shfl_xor(aB.x, 8, 32);  aB.y += __shfl_xor(aB.y, 8, 32);
    aB.z += __shfl_xor(aB.z, 8, 32);  aB.w += __shfl_xor(aB.w, 8, 32);
    aB.x += __shfl_xor(aB.x, 16, 32); aB.y += __shfl_xor(aB.y, 16, 32);
    aB.z += __shfl_xor(aB.z, 16, 32); aB.w += __shfl_xor(aB.w, 16, 32);
    float4 svA = rowf4[iA * 8 + c], svB = rowf4[iB * 8 + c];
    float diA = dis[iA], diB = dis[iB];
    aA.x = (aA.x + svA.x) * diA; aA.y = (aA.y + svA.y) * diA;
    aA.z = (aA.z + svA.z) * diA; aA.w = (aA.w + svA.w) * diA;
    aB.x = (aB.x + svB.x) * diB; aB.y = (aB.y + svB.y) * diB;
    aB.z = (aB.z + svB.z) * diB; aB.w = (aB.w + svB.w) * diB;
    if (l < 8) ((float4*)arow[g * 2])[l] = aA;
    else if (l < 16) ((float4*)arow[g * 2 + 1])[l - 8] = aB;
    float accA = 0.f, accB = 0.f;
#pragma unroll
    for (int q = 0; q < 8; ++q) {
        float4 qa = ((const float4*)arow[g * 2])[q];
        float4 qb = ((const float4*)arow[g * 2 + 1])[q];
        accA = fmaf(qa.x, wcol[4 * q + 0],
               fmaf(qa.y, wcol[4 * q + 1],
               fmaf(qa.z, wcol[4 * q + 2],
               fmaf(qa.w, wcol[4 * q + 3], accA))));
        accB = fmaf(qb.x, wcol[4 * q + 0],
               fmaf(qb.y, wcol[4 * q + 1],
               fmaf(qb.z, wcol[4 * q + 2],
               fmaf(qb.w, wcol[4 * q + 3], accB))));
    }
    float vA_ = accA + b[f]; vA_ = vA_ > 0.f ? vA_ : 0.f;
    float vB_ = accB + b[f]; vB_ = vB_ > 0.f ? vB_ : 0.f;
    hout[iA * D + f] = vA_ * diA;
    hout[iB * D + f] = vB_ * diB;
}

// ---------- heads: 2-node batched gather, two transforms + 32->1 dots ----------
__global__ __launch_bounds__(256) void k_heads(
    const float* __restrict__ hsc, const int* __restrict__ row,
    const int* __restrict__ csr, const float* __restrict__ dis,
    const float* __restrict__ W1, const float* __restrict__ b1,
    const float* __restrict__ W2, const float* __restrict__ b2,
    const float* __restrict__ fw1, const float* __restrict__ fb1,
    const float* __restrict__ fw2, const float* __restrict__ fb2,
    float* __restrict__ out) {
    __shared__ float arow[16][32];
    int g = threadIdx.x >> 5, l = threadIdx.x & 31, f = l;
    int gg = blockIdx.x * 8 + g;
    int iA = gg * 2, iB = iA + 1;
    float wc1[D], wc2[D];
#pragma unroll
    for (int k = 0; k < D; ++k) { wc1[k] = W1[k * D + f]; wc2[k] = W2[k * D + f]; }
    int c = l & 7, l16 = l & 15, sub = l >> 3;
    const float4* rowf4 = (const float4*)hsc;
    int rsA = row[iA], mid = row[iB], reB = row[iB + 1];
    float4 aA = make_float4(0.f, 0.f, 0.f, 0.f);
    float4 aB = make_float4(0.f, 0.f, 0.f, 0.f);
    int jA = rsA, jB = mid;
    int csA = csr[jA + l16], csB = csr[jB + l16];
    while (jA < mid && jB < reB) {
        int nA = csr[jA + 16 + l16], nB = csr[jB + 16 + l16];
        float4 vA[4], vB[4];
#pragma unroll
        for (int it = 0; it < 4; ++it)
            if (jA + it * 4 < mid) { int s = __shfl(csA, it * 4 + sub, 32); vA[it] = rowf4[s * 8 + c]; }
#pragma unroll
        for (int it = 0; it < 4; ++it)
            if (jB + it * 4 < reB) { int s = __shfl(csB, it * 4 + sub, 32); vB[it] = rowf4[s * 8 + c]; }
#pragma unroll
        for (int it = 0; it < 4; ++it) {
            if (jA + it * 4 < mid) { aA.x += vA[it].x; aA.y += vA[it].y; aA.z += vA[it].z; aA.w += vA[it].w; }
            if (jB + it * 4 < reB) { aB.x += vB[it].x; aB.y += vB[it].y; aB.z += vB[it].z; aB.w += vB[it].w; }
        }
        csA = nA; csB = nB; jA += 16; jB += 16;
    }
    while (jA < mid) {
        int nA = csr[jA + 16 + l16];
        float4 vA[4];
#pragma unroll
        for (int it = 0; it < 4; ++it)
            if (jA + it * 4 < mid) { int s = __shfl(csA, it * 4 + sub, 32); vA[it] = rowf4[s * 8 + c]; }
#pragma unroll
        for (int it = 0; it < 4; ++it)
            if (jA + it * 4 < mid) { aA.x += vA[it].x; aA.y += vA[it].y; aA.z += vA[it].z; aA.w += vA[it].w; }
        csA = nA; jA += 16;
    }
    while (jB < reB) {
        int nB = csr[jB + 16 + l16];
        float4 vB[4];
#pragma unroll
        for (int it = 0; it < 4; ++it)
            if (jB + it * 4 < reB) { int s = __shfl(csB, it * 4 + sub, 32); vB[it] = rowf4[s * 8 + c]; }
#pragma unroll
        for (int it = 0; it < 4; ++it)
            if (jB + it * 4 < reB) { aB.x += vB[it].x; aB.y += vB[it].y; aB.z += vB[it].z; aB.w += vB[it].w; }
        csB = nB; jB += 16;
    }
    aA.x += __shfl_xor(aA.x, 8, 32);  aA.y += __shfl_xor(aA.y, 8, 32);
    aA.z += __shfl_xor(aA.z, 8, 32);  aA.w += __shfl_xor(aA.w, 8, 32);
    aA.x += __shfl_xor(aA.x, 16, 32); aA.y += __shfl_xor(aA.y, 16, 32);
    aA.z += __shfl_xor(aA.z, 16, 32); aA.w += __shfl_xor(aA.w, 16, 32);
    aB.x += __shfl_xor(aB.x, 8, 32);  aB.y += __shfl_xor(aB.y, 8, 32);
    aB.z += __shfl_xor(aB.z, 8, 32);  aB.w += __shfl_xor(aB.w, 8, 32);
    aB.x += __shfl_xor(aB.x, 16, 32); aB.y += __shfl_xor(aB.y, 16, 32);
    aB.z += __shfl_xor(aB.z, 16, 32); aB.w += __shfl_xor(aB.w, 16, 32);
    float4 svA = rowf4[iA * 8 + c], svB = rowf4[iB * 8 + c];
    float diA = dis[iA], diB = dis[iB];
    aA.x = (aA.x + svA.x) * diA; aA.y = (aA.y + svA.y) * diA;
    aA.z = (aA.z + svA.z) * diA; aA.w = (aA.w + svA.w) * diA;
    aB.x = (aB.x + svB.x) * diB; aB.y = (aB.y + svB.y) * diB;
    aB.z = (aB.z + svB.z) * diB; aB.w = (aB.w + svB.w) * diB;
    if (l < 8) ((float4*)arow[g * 2])[l] = aA;
    else if (l < 16) ((float4*)arow[g * 2 + 1])[l - 8] = aB;
    float a1A = 0.f, a2A = 0.f, a1B = 0.f, a2B = 0.f;
#pragma unroll
    for (int q = 0; q < 8; ++q) {
        float4 qa = ((const float4*)arow[g * 2])[q];
        float4 qb = ((const float4*)arow[g * 2 + 1])[q];
        a1A = fmaf(qa.x, wc1[4 * q + 0], fmaf(qa.y, wc1[4 * q + 1],
              fmaf(qa.z, wc1[4 * q + 2], fmaf(qa.w, wc1[4 * q + 3], a1A))));
        a2A = fmaf(qa.x, wc2[4 * q + 0], fmaf(qa.y, wc2[4 * q + 1],
              fmaf(qa.z, wc2[4 * q + 2], fmaf(qa.w, wc2[4 * q + 3], a2A))));
        a1B = fmaf(qb.x, wc1[4 * q + 0], fmaf(qb.y, wc1[4 * q + 1],
              fmaf(qb.z, wc1[4 * q + 2], fmaf(qb.w, wc1[4 * q + 3], a1B))));
        a2B = fmaf(qb.x, wc2[4 * q + 0], fmaf(qb.y, wc2[4 * q + 1],
              fmaf(qb.z, wc2[4 * q + 2], fmaf(qb.w, wc2[4 * q + 3], a2B))));
    }
    float v1A = a1A + b1[f]; v1A = (v1A > 0.f ? v1A : 0.f) * fw1[f];
    float v2A = a2A + b2[f]; v2A = (v2A > 0.f ? v2A : 0.f) * fw2[f];
    float v1B = a1B + b1[f]; v1B = (v1B > 0.f ? v1B : 0.f) * fw1[f];
    float v2B = a2B + b2[f]; v2B = (v2B > 0.f ? v2B : 0.f) * fw2[f];
#pragma unroll
    for (int o = 16; o > 0; o >>= 1) {
        v1A += __shfl_down(v1A, o, 32);
        v2A += __shfl_down(v2A, o, 32);
        v1B += __shfl_down(v1B, o, 32);
        v2B += __shfl_down(v2B, o, 32);
    }
    if (l == 0) {
        float4 o4 = make_float4(v1A + fb1[0], v2A + fb2[0], v1B + fb1[0], v2B + fb2[0]);
        *(float4*)&out[iA * 2] = o4;  // iA even -> 16B aligned
    }
}

extern "C" void kernel_launch(void* const* d_in, const int* in_sizes, int n_in,
                              void* d_out, int out_size, void* d_ws, size_t ws_size,
                              hipStream_t stream) {
    const float* x       = (const float*)d_in[0];
    const int*   eidx    = (const int*)d_in[1];
    const float* fc1_w   = (const float*)d_in[2];
    const float* fc1_b   = (const float*)d_in[3];
    const float* conv1_w = (const float*)d_in[4];
    const float* conv1_b = (const float*)d_in[5];
    const float* conv2_w = (const float*)d_in[6];
    const float* conv2_b = (const float*)d_in[7];
    const float* c31_w   = (const float*)d_in[8];
    const float* c31_b   = (const float*)d_in[9];
    const float* c32_w   = (const float*)d_in[10];
    const float* c32_b   = (const float*)d_in[11];
    const float* fc21_w  = (const float*)d_in[12];
    const float* fc21_b  = (const float*)d_in[13];
    const float* fc22_w  = (const float*)d_in[14];
    const float* fc22_b  = (const float*)d_in[15];
    float* out = (float*)d_out;

    const int* src = eidx;            // edge_index[0]
    const int* dst = eidx + N_EDGES;  // edge_index[1]

    // ----- workspace layout (int units; 16B alignment preserved) -----
    int*   wsb    = (int*)d_ws;
    int*   csr    = wsb;                        // CSR_CAP
    int*   irow   = wsb + 2850064;              // 150,004
    int*   bstart = wsb + 3000068;              // 1,174
    int*   pbase  = wsb + 3001242;              // 1,174
    float* dis    = (float*)(wsb + 3002416);    // 150,000
    float* HA     = (float*)(wsb + 3152416);    // 4,800,032 floats
    float* HB     = (float*)(wsb + 7952448);    // 4,800,032 floats
    // transient aliases inside HA (dead before k_layer writes HA):
    int*    cnt  = (int*)HA;                    // 686,792
    int*    ebuf = (int*)HA + 700000;           // 2,400,000
    float4* xd   = (float4*)((int*)HA + 3100016);  // (N+1) float4
    // deg aliases HB low (dead before k_layer1f writes HB):
    int*    deg  = (int*)HB;                    // 150,000

    const int BLK = 256;
    const int gL1 = N_NODES / 16;                   // 9375 (2-node groups, exact)

    // ----- CSR build (no global atomics) -----
    kA_hist<<<NCHK, BLK, 0, stream>>>(dst, cnt);
    kS1<<<(NBUCK + 31) / 32, BLK, 0, stream>>>(cnt, bstart);
    k_scan_small<<<1, BLK, 0, stream>>>(bstart, NBUCK);
    kB_scatter<<<NCHK, BLK, 0, stream>>>(src, dst, cnt, bstart, ebuf);
    kC1<<<NBUCK, BLK, 0, stream>>>(ebuf, bstart, (const float2*)x, deg, dis, xd, pbase);
    k_scan_small<<<1, BLK, 0, stream>>>(pbase, NBUCK);
    kC3<<<NBUCK, BLK, 0, stream>>>(ebuf, bstart, deg, pbase, csr, irow, HA, HB);

    // ----- network -----
    k_layer1f<<<gL1, BLK, 0, stream>>>(xd, irow, csr, fc1_w, fc1_b, conv1_w, conv1_b, HB);
    k_layer<<<gL1, BLK, 0, stream>>>(HB, irow, csr, dis, conv2_w, conv2_b, HA);
    k_heads<<<gL1, BLK, 0, stream>>>(HA, irow, csr, dis, c31_w, c31_b, c32_w, c32_b,
                                     fc21_w, fc21_b, fc22_w, fc22_b, out);
}